// Round 7
// baseline (2915.792 us; speedup 1.0000x reference)
//
#include <hip/hip_runtime.h>
#include <hip/hip_bf16.h>
#include <math.h>

#define TT 512
#define BB 128
#define DD 256
#define HH 512
#define EPSF 1e-7f
#define NBG 8     // b-groups of 16 rows (independent LSTM chains)
#define NKS 16    // k-slices of 32 cols per b-group

typedef unsigned int u32;
typedef unsigned short u16;
typedef __attribute__((ext_vector_type(8))) short bf16x8;
typedef __attribute__((ext_vector_type(4))) float f32x4;
typedef __attribute__((ext_vector_type(4))) u32 u32x4;

__device__ __forceinline__ u16 f2b(float x){
  __hip_bfloat16 b = __float2bfloat16(x);
  union { __hip_bfloat16 h; u16 u; } c; c.h = b; return c.u;
}
__device__ __forceinline__ bf16x8 as_b8(u32x4 u){
  union { u32x4 a; bf16x8 b; } c; c.a = u; return c.b;
}
// MALL-coherent (system-ish) ops: sc0 sc1 bypass L1+L2 both ways, so producer
// stores and consumer loads meet at the MALL with zero cache-maintenance ops.
__device__ __forceinline__ u32x4 ld16_sys(const void* p){
  u32x4 r;
  asm volatile("global_load_dwordx4 %0, %1, off sc0 sc1" : "=v"(r) : "v"(p) : "memory");
  return r;
}
__device__ __forceinline__ void st4_sys(void* p, u32 v){
  asm volatile("global_store_dword %0, %1, off sc0 sc1" :: "v"(p), "v"(v) : "memory");
}

// ---------------------------------------------------------------------------
// Setup: masks zx/zh, combined bias, bf16 Wx/Wh, hm32 tag-invalidation.
// ---------------------------------------------------------------------------
__global__ void setup_kernel(const float* __restrict__ ux, const float* __restrict__ uh,
                             const float* __restrict__ p_logit,
                             const float* __restrict__ bx, const float* __restrict__ bh,
                             const float* __restrict__ Wx, const float* __restrict__ Wh,
                             float* __restrict__ zx, float* __restrict__ zh,
                             float* __restrict__ bias,
                             u16* __restrict__ wxb, u16* __restrict__ whb,
                             u32* __restrict__ hm32){
  const int i = blockIdx.x*256 + threadIdx.x;
  const float p = 1.0f/(1.0f+expf(-p_logit[0]));
  const float lp = logf(p+EPSF) - logf(1.0f-p+EPSF);
  const float inv1mp = 1.0f/(1.0f-p);
  const int S1 = 4*BB*DD;             // zx end      131072
  const int S2 = S1 + 4*BB*HH;        // zh end      393216
  const int S3 = S2 + 4*HH;           // bias end    395264
  const int S4 = S3 + 4*HH*DD;        // wxb end     919552
  const int S5 = S4 + 4*HH*HH;        // whb end     1968128
  const int S6 = S5 + 2*NBG*4*16*HH;  // hm32 end    2492416
  if (i < S1){
    float u = ux[i];
    float l = (lp + logf(u+EPSF) - logf(1.0f-u+EPSF)) * 10.0f;  // /TEMP
    zx[i] = (1.0f - 1.0f/(1.0f+expf(-l))) * inv1mp;
  } else if (i < S2){
    int j = i - S1;
    float u = uh[j];
    float l = (lp + logf(u+EPSF) - logf(1.0f-u+EPSF)) * 10.0f;
    zh[j] = (1.0f - 1.0f/(1.0f+expf(-l))) * inv1mp;
  } else if (i < S3){
    int j = i - S2;
    bias[j] = bx[j] + bh[j];
  } else if (i < S4){
    int j = i - S3;
    wxb[j] = f2b(Wx[j]);
  } else if (i < S5){
    int j = i - S4;
    whb[j] = f2b(Wh[j]);
  } else if (i < S6){
    hm32[i - S5] = 0xFFFF0000u;   // tag 0xFFFF never matches any step
  }
}

// ---------------------------------------------------------------------------
// xim[t][g][b][d] = bf16(input[t][b][d] * zx[g][b][d]); input read once.
// ---------------------------------------------------------------------------
__global__ void xim_kernel(const float* __restrict__ input, const float* __restrict__ zx,
                           u16* __restrict__ xim){
  const int i = blockIdx.x*256 + threadIdx.x;   // (t,b,d-octet)
  const int d = (i & 31) * 8;
  const int rest = i >> 5;             // t*BB + b
  const int b = rest & (BB-1);
  const int t = rest >> 7;
  const float* ip = input + ((size_t)t*BB + b)*DD + d;
  const float4 x0 = *(const float4*)ip;
  const float4 x1 = *(const float4*)(ip+4);
  #pragma unroll
  for (int g = 0; g < 4; g++){
    const float* zp = zx + ((size_t)g*BB + b)*DD + d;
    const float4 z0 = *(const float4*)zp;
    const float4 z1 = *(const float4*)(zp+4);
    union { u16 s[8]; uint4 v; } o;
    o.s[0]=f2b(x0.x*z0.x); o.s[1]=f2b(x0.y*z0.y); o.s[2]=f2b(x0.z*z0.z); o.s[3]=f2b(x0.w*z0.w);
    o.s[4]=f2b(x1.x*z1.x); o.s[5]=f2b(x1.y*z1.y); o.s[6]=f2b(x1.z*z1.z); o.s[7]=f2b(x1.w*z1.w);
    *(uint4*)(xim + (((size_t)t*4 + g)*BB + b)*DD + d) = o.v;
  }
}

// ---------------------------------------------------------------------------
// Persistent LSTM, tagged-data exchange (no flags, no drains, no claims).
// 128 blocks = 8 b-groups(16 b) x 16 k-slices(32 k); 512 thr = 8 waves.
// hm element = u32: high16 = step tag, low16 = bf16(h*zh).  Producer threads
// store their own 4 tagged words; consumers poll the data until every tag
// matches t-1 (per-word atomicity makes torn batches detectable).
// ---------------------------------------------------------------------------
__global__ __launch_bounds__(512, 2)
void lstm_persist(const u16* __restrict__ xim,   // [T][4][B][D]
                  const u16* __restrict__ whb,   // [4][H][H]
                  const u16* __restrict__ wxb,   // [4][H][D]
                  const float* __restrict__ zh,  // [4][B][H]
                  const float* __restrict__ bias,// [4][H]
                  u32* __restrict__ hm32,        // [2][NBG][4][16][H] tagged
                  float* __restrict__ hn,        // [T][B][H]
                  float* __restrict__ htc)       // [2][B][H]
{
  __shared__ float pl[8][16][36];   // partial gates [wid][b_local][k_local], padded

  const int bid = blockIdx.x;
  const int bg = bid & 7, ks = bid >> 3;
  const int b0 = bg*16, k0 = ks*32;
  const int tid = threadIdx.x;
  const int wid = tid >> 6, lane = tid & 63;
  const int g = wid & 3, qh = wid >> 2;
  const int arow = lane & 15, kq = lane >> 4;

  // ---- weights into registers ----
  u32x4 whf[2][8], wxf[2][4];
  #pragma unroll
  for (int nt = 0; nt < 2; nt++){
    #pragma unroll
    for (int c = 0; c < 8; c++)
      whf[nt][c] = *(const u32x4*)(whb + (((size_t)g*HH + k0 + nt*16 + arow)*HH
                                          + qh*256 + c*32 + kq*8));
    #pragma unroll
    for (int c = 0; c < 4; c++)
      wxf[nt][c] = *(const u32x4*)(wxb + (((size_t)g*HH + k0 + nt*16 + arow)*DD
                                          + qh*128 + c*32 + kq*8));
  }

  // per-thread epilogue constants (1 cell per thread)
  const int ebl = tid >> 5, ekl = tid & 31;
  float bias4[4], zhe[4];
  #pragma unroll
  for (int gg = 0; gg < 4; gg++){
    bias4[gg] = bias[gg*HH + k0 + ekl];
    zhe[gg]   = zh[((size_t)gg*BB + b0 + ebl)*HH + k0 + ekl];
  }
  float creg = 0.f;

  for (int t = 0; t < TT; t++){
    // xa loads + x-MFMAs: independent of the exchange, overlap the wait
    u32x4 xa[4];
    #pragma unroll
    for (int c = 0; c < 4; c++)
      xa[c] = *(const u32x4*)(xim + ((((size_t)t*4 + g)*BB + b0 + arow)*DD
                                     + qh*128 + c*32 + kq*8));
    f32x4 acc0 = {0.f,0.f,0.f,0.f}, acc1 = {0.f,0.f,0.f,0.f};
    #pragma unroll
    for (int c = 0; c < 4; c++){
      acc0 = __builtin_amdgcn_mfma_f32_16x16x32_bf16(as_b8(xa[c]), as_b8(wxf[0][c]), acc0, 0,0,0);
      acc1 = __builtin_amdgcn_mfma_f32_16x16x32_bf16(as_b8(xa[c]), as_b8(wxf[1][c]), acc1, 0,0,0);
    }

    if (t > 0){
      // poll the tagged data itself: one batch of 16x16B loads per retry
      const u32* hb = hm32 + ((size_t)((t-1)&1)*NBG + bg)*(4*16*HH)
                           + (g*16 + arow)*HH + qh*256 + kq*8;
      const u32 tw = (u32)(t-1) << 16;
      u32x4 w[16];
      while (1){
        #pragma unroll
        for (int c = 0; c < 8; c++){
          w[2*c]   = ld16_sys(hb + c*32);
          w[2*c+1] = ld16_sys(hb + c*32 + 4);
        }
        asm volatile("s_waitcnt vmcnt(0)" ::: "memory");
        __builtin_amdgcn_sched_barrier(0);
        u32 bad = 0;
        #pragma unroll
        for (int c = 0; c < 16; c++){
          bad |= (w[c].x ^ tw); bad |= (w[c].y ^ tw);
          bad |= (w[c].z ^ tw); bad |= (w[c].w ^ tw);
        }
        if (__all((bad & 0xffff0000u) == 0u)) break;
      }
      // unpack low16 pairs -> bf16x8 fragments, then h-MFMAs
      #pragma unroll
      for (int c = 0; c < 8; c++){
        u32x4 lo = w[2*c], hi = w[2*c+1];
        u32x4 hv;
        hv.x = __builtin_amdgcn_perm(lo.y, lo.x, 0x05040100u);
        hv.y = __builtin_amdgcn_perm(lo.w, lo.z, 0x05040100u);
        hv.z = __builtin_amdgcn_perm(hi.y, hi.x, 0x05040100u);
        hv.w = __builtin_amdgcn_perm(hi.w, hi.z, 0x05040100u);
        acc0 = __builtin_amdgcn_mfma_f32_16x16x32_bf16(as_b8(hv), as_b8(whf[0][c]), acc0, 0,0,0);
        acc1 = __builtin_amdgcn_mfma_f32_16x16x32_bf16(as_b8(hv), as_b8(whf[1][c]), acc1, 0,0,0);
      }
    }

    // D-frag: b_local = kq*4+r, k_local = nt*16 + arow
    #pragma unroll
    for (int r = 0; r < 4; r++){
      pl[wid][kq*4 + r][arow]      = acc0[r];
      pl[wid][kq*4 + r][16 + arow] = acc1[r];
    }
    __syncthreads();   // [B] pl complete

    { // epilogue: all 512 threads, one (b,k) cell each; store own tagged hm
      float gv[4];
      #pragma unroll
      for (int gg = 0; gg < 4; gg++)
        gv[gg] = pl[gg][ebl][ekl] + pl[4+gg][ebl][ekl] + bias4[gg];
      float iv = 1.f/(1.f + __expf(-gv[0]));
      float fv = 1.f/(1.f + __expf(-gv[1]));
      float ov = 1.f/(1.f + __expf(-gv[2]));
      float e2g = __expf(2.f*gv[3]);
      float gc = 1.f - 2.f/(e2g + 1.f);          // tanh(g)
      creg = fv*creg + iv*gc;
      float e2c = __expf(2.f*creg);
      float th = 1.f - 2.f/(e2c + 1.f);          // tanh(c)
      float hv = ov*th;
      const u32 tagw = (u32)t << 16;
      u32* hw = hm32 + ((size_t)(t&1)*NBG + bg)*(4*16*HH) + ebl*HH + k0 + ekl;
      #pragma unroll
      for (int gg = 0; gg < 4; gg++)
        st4_sys(hw + gg*16*HH, tagw | (u32)f2b(hv * zhe[gg]));
      hn[(size_t)t*BB*HH + (size_t)(b0 + ebl)*HH + k0 + ekl] = hv;
      if (t == TT-1){
        const size_t ci = (size_t)(b0 + ebl)*HH + k0 + ekl;
        htc[ci] = hv;
        htc[(size_t)BB*HH + ci] = creg;
      }
    }
    __syncthreads();   // [C] pl reads done -> safe to write pl(t+1)
  }
}

// ---------------------------------------------------------------------------
extern "C" void kernel_launch(void* const* d_in, const int* in_sizes, int n_in,
                              void* d_out, int out_size, void* d_ws, size_t ws_size,
                              hipStream_t stream){
  const float* input   = (const float*)d_in[0];
  const float* ux      = (const float*)d_in[1];
  const float* uh      = (const float*)d_in[2];
  const float* p_logit = (const float*)d_in[3];
  const float* Wx      = (const float*)d_in[4];
  const float* bx      = (const float*)d_in[5];
  const float* Wh      = (const float*)d_in[6];
  const float* bh      = (const float*)d_in[7];

  char* ws = (char*)d_ws;
  const size_t o_zx  = 0;                        // 4*B*D f32      = 524288
  const size_t o_zh  = o_zx  + 524288;           // 4*B*H f32      = 1048576
  const size_t o_b   = o_zh  + 1048576;          // 4*H f32        = 8192
  const size_t o_wxb = o_b   + 8192;             // 4*H*D bf16     = 1048576
  const size_t o_whb = o_wxb + 1048576;          // 4*H*H bf16     = 2097152
  const size_t o_xim = o_whb + 2097152;          // T*4*B*D bf16   = 134217728
  const size_t o_hm  = o_xim + 134217728;        // 2*8*4*16*H u32 = 2097152
  const size_t need  = o_hm + 2097152;
  if (ws_size < need) return;

  float* zx   = (float*)(ws + o_zx);
  float* zh   = (float*)(ws + o_zh);
  float* bias = (float*)(ws + o_b);
  u16*   wxb  = (u16*)(ws + o_wxb);
  u16*   whb  = (u16*)(ws + o_whb);
  u16*   xim  = (u16*)(ws + o_xim);
  u32*   hm32 = (u32*)(ws + o_hm);

  float* out_hn = (float*)d_out;
  float* out_ht = out_hn + (size_t)TT*BB*HH;

  setup_kernel<<<9736, 256, 0, stream>>>(ux, uh, p_logit, bx, bh, Wx, Wh,
                                         zx, zh, bias, wxb, whb, hm32);
  xim_kernel<<<8192, 256, 0, stream>>>(input, zx, xim);
  lstm_persist<<<NBG*NKS, 512, 0, stream>>>(xim, whb, wxb, zh, bias,
                                            hm32, out_hn, out_ht);
}